// Round 1
// baseline (3085.241 us; speedup 1.0000x reference)
//
#include <hip/hip_runtime.h>
#include <hip/hip_fp16.h>

#define FD 128          // feature dim
#define SW 32           // feature-slice width: 32 halfs = 64B; slice state = N*SW*2B = 3.2MB < 4MB per-XCD L2
#define NSLICE 4        // FD / SW
#define RPB 4           // rows (waves) per block; block = 256 threads
#define SUBS 8          // edges in flight per wave; 8 lanes x 8B cover one 64B row-slice
// NOTE: algebraic elimination of b_{M-1} assumes M >= 4 (here M = 30).
// Slice s is pinned to XCDs {2s,2s+1} via blockIdx%8 round-robin (perf-only assumption).

// ---------------- CSR build ----------------

__global__ void zero_i32(int* __restrict__ p, int n) {
  int i = blockIdx.x * blockDim.x + threadIdx.x;
  if (i < n) p[i] = 0;
}

__global__ void hist_kernel(const int* __restrict__ rows, int* __restrict__ cnt, int nnz) {
  int i = blockIdx.x * blockDim.x + threadIdx.x;
  if (i < nnz) atomicAdd(&cnt[rows[i]], 1);
}

__global__ void block_reduce(const int* __restrict__ cnt, int* __restrict__ bsum, int n) {
  __shared__ int sm[256];
  int i = blockIdx.x * 256 + threadIdx.x;
  sm[threadIdx.x] = (i < n) ? cnt[i] : 0;
  __syncthreads();
  for (int off = 128; off > 0; off >>= 1) {
    if (threadIdx.x < off) sm[threadIdx.x] += sm[threadIdx.x + off];
    __syncthreads();
  }
  if (threadIdx.x == 0) bsum[blockIdx.x] = sm[0];
}

__global__ void scan_bsum(const int* __restrict__ bsum, int* __restrict__ bpre, int nb) {
  __shared__ int sm[1024];
  const int tid = threadIdx.x;
  sm[tid] = (tid < nb) ? bsum[tid] : 0;
  __syncthreads();
  for (int off = 1; off < 1024; off <<= 1) {
    int t = (tid >= off) ? sm[tid - off] : 0;
    __syncthreads();
    sm[tid] += t;
    __syncthreads();
  }
  if (tid < nb) bpre[tid] = (tid == 0) ? 0 : sm[tid - 1];
}

__global__ void block_scan(const int* __restrict__ cnt, const int* __restrict__ bpre,
                           int* __restrict__ row_ptr, int n) {
  __shared__ int sm[256];
  const int tid = threadIdx.x;
  int i = blockIdx.x * 256 + tid;
  sm[tid] = (i < n) ? cnt[i] : 0;
  __syncthreads();
  for (int off = 1; off < 256; off <<= 1) {
    int t = (tid >= off) ? sm[tid - off] : 0;
    __syncthreads();
    sm[tid] += t;
    __syncthreads();
  }
  if (i < n) row_ptr[i + 1] = sm[tid] + bpre[blockIdx.x];
  if (i == 0) row_ptr[0] = 0;
}

__global__ void copy_i32(const int* __restrict__ src, int* __restrict__ dst, int n) {
  int i = blockIdx.x * blockDim.x + threadIdx.x;
  if (i < n) dst[i] = src[i];
}

// packed edge scatter: one 8B store per edge
__global__ void scatter_kernel(const int* __restrict__ rows, const int* __restrict__ cols,
                               const float* __restrict__ vals, int* __restrict__ fill,
                               int2* __restrict__ pk, int nnz) {
  int i = blockIdx.x * blockDim.x + threadIdx.x;
  if (i < nnz) {
    int r = rows[i];
    int pos = atomicAdd(&fill[r], 1);
    pk[pos] = make_int2(cols[i], __float_as_int(vals[i]));
  }
}

__global__ void f32_to_f16(const float* __restrict__ src, __half* __restrict__ dst, int n4) {
  int i = blockIdx.x * blockDim.x + threadIdx.x;
  if (i < n4) {
    float4 v = ((const float4*)src)[i];
    __half2* d = (__half2*)dst + 2 * (size_t)i;
    d[0] = __floats2half2_rn(v.x, v.y);
    d[1] = __floats2half2_rn(v.z, v.w);
  }
}

// ---------------- nontemporal helpers (protect the L2-resident slice) ----------------

typedef int v2i __attribute__((ext_vector_type(2)));
typedef unsigned int v2u __attribute__((ext_vector_type(2)));
typedef float v4f __attribute__((ext_vector_type(4)));

__device__ __forceinline__ int2 nt_ld_i2(const int2* p) {
  v2i v = __builtin_nontemporal_load((const v2i*)p);
  return make_int2(v.x, v.y);
}
__device__ __forceinline__ uint2 nt_ld_u2(const uint2* p) {
  v2u v = __builtin_nontemporal_load((const v2u*)p);
  return make_uint2(v.x, v.y);
}
__device__ __forceinline__ float4 nt_ld_f4(const float4* p) {
  v4f v = __builtin_nontemporal_load((const v4f*)p);
  return make_float4(v.x, v.y, v.z, v.w);
}
__device__ __forceinline__ void nt_st_f4(float4* p, float4 x) {
  v4f v = {x.x, x.y, x.z, x.w};
  __builtin_nontemporal_store(v, (v4f*)p);
}

// ---------------- sliced gather ----------------
// Wave = 1 row-slice. sub = lane>>3 picks 1 of 8 edges; fl = lane&7 picks a
// 4-feature uint2 (8B) within the 64B slice row. One load instruction covers
// 8 edges x 64B = 512B (8 distinct lines). T must point at slice start.

__device__ __forceinline__ void fma_edge8(const __half* __restrict__ T, int c, float v,
                                          int fl, float2 acc[2]) {
  uint2 raw = ((const uint2*)(T + (size_t)c * FD))[fl];
  const __half2* h = (const __half2*)&raw;
  float2 x0 = __half22float2(h[0]);
  float2 x1 = __half22float2(h[1]);
  acc[0].x = fmaf(v, x0.x, acc[0].x); acc[0].y = fmaf(v, x0.y, acc[0].y);
  acc[1].x = fmaf(v, x1.x, acc[1].x); acc[1].y = fmaf(v, x1.y, acc[1].y);
}

__device__ __forceinline__ void gather_row(const int* __restrict__ rp,
                                           const int2* __restrict__ pk,
                                           const __half* __restrict__ T,
                                           int r, int sub, int fl, float2 acc[2]) {
  int e = rp[r];
  const int end = rp[r + 1];
  // 16 edges per iteration -> 2 gather instructions in flight
  for (; e + 16 <= end; e += 16) {
    int2 cv0 = nt_ld_i2(pk + e + sub);
    int2 cv1 = nt_ld_i2(pk + e + 8 + sub);
    fma_edge8(T, cv0.x, __int_as_float(cv0.y), fl, acc);
    fma_edge8(T, cv1.x, __int_as_float(cv1.y), fl, acc);
  }
  if (e + 8 <= end) {
    int2 cv = nt_ld_i2(pk + e + sub);
    fma_edge8(T, cv.x, __int_as_float(cv.y), fl, acc);
    e += 8;
  }
  if (e < end) {
    int idx = e + sub;
    int2 cv = nt_ld_i2(pk + min(idx, end - 1));
    float v = (idx < end) ? __int_as_float(cv.y) : 0.f;
    fma_edge8(T, cv.x, v, fl, acc);
  }
}

__device__ __forceinline__ void reduce_subs(float2 acc[2]) {
#pragma unroll
  for (int m = 8; m < 64; m <<= 1) {
#pragma unroll
    for (int q = 0; q < 2; ++q) {
      acc[q].x += __shfl_xor(acc[q].x, m, 64);
      acc[q].y += __shfl_xor(acc[q].y, m, 64);
    }
  }
}

// block -> (slice, row-block) mapping pinned to XCD pairs via blockIdx%8.
// bid = 8t + x : xcd = x, slice = x>>1, rb = 2t + (x&1). Bijective onto
// [0,NSLICE) x [0,rbs) when grid = 8*ceil(rbs/2).
__device__ __forceinline__ void decode_bid(int bid, int rbs, int& slice, int& rb) {
  slice = (bid >> 1) & 3;
  rb = ((bid >> 3) << 1) | (bid & 1);
}

// ---------------- Clenshaw steps (per feature-slice) ----------------
// b_k = g2*(L @ src) - p + ck_eff * X   (fp16 state, fp32 math)
// flags: bit0 = read p from pd; bit1 = ck_eff = c_k - c_{M-1}; bit2 = g2 = 2*c_{M-1}, src = Xh.

__global__ __launch_bounds__(256) void clen_step(
    const int* __restrict__ rp, const int2* __restrict__ pk,
    const __half* __restrict__ src, const __half* __restrict__ Xh, __half* pd,
    const float* __restrict__ coeffs, int k, int flags, int M, int n, int rbs) {
  int slice, rb;
  decode_bid(blockIdx.x, rbs, slice, rb);
  if (rb >= rbs) return;
  const int lane = threadIdx.x & 63;
  const int sub = lane >> 3, fl = lane & 7;
  const int r = rb * RPB + (threadIdx.x >> 6);
  if (r >= n) return;
  float2 acc[2] = {{0.f,0.f},{0.f,0.f}};
  gather_row(rp, pk, src + slice * SW, r, sub, fl, acc);
  reduce_subs(acc);
  if (sub == 0) {
    float ck = coeffs[k];
    if (flags & 2) ck -= coeffs[M - 1];
    const float g2 = (flags & 4) ? 2.f * coeffs[M - 1] : 2.f;
    const size_t off = (size_t)r * FD + slice * SW;
    uint2 xr = nt_ld_u2((const uint2*)(Xh + off) + fl);
    const __half2* xh = (const __half2*)&xr;
    float2 p[2] = {{0.f,0.f},{0.f,0.f}};
    if (flags & 1) {
      uint2 pr = nt_ld_u2((const uint2*)(pd + off) + fl);
      const __half2* ph = (const __half2*)&pr;
      p[0] = __half22float2(ph[0]);
      p[1] = __half22float2(ph[1]);
    }
    uint2 orr;
    __half2* oh = (__half2*)&orr;
#pragma unroll
    for (int q = 0; q < 2; ++q) {
      float2 x = __half22float2(xh[q]);
      float tx = fmaf(g2, acc[q].x, fmaf(ck, x.x, -p[q].x));
      float ty = fmaf(g2, acc[q].y, fmaf(ck, x.y, -p[q].y));
      oh[q] = __floats2half2_rn(tx, ty);
    }
    // normal (cached) store: this slice is gathered next step by the same XCD pair
    ((uint2*)(pd + off))[fl] = orr;
  }
}

// out = c0*X + L @ b1 - b2   (fp32 X and output)
__global__ __launch_bounds__(256) void clen_final(
    const int* __restrict__ rp, const int2* __restrict__ pk,
    const __half* __restrict__ b1, const __half* __restrict__ b2,
    const float* __restrict__ X, float* __restrict__ out,
    const float* __restrict__ coeffs, int n, int rbs) {
  int slice, rb;
  decode_bid(blockIdx.x, rbs, slice, rb);
  if (rb >= rbs) return;
  const int lane = threadIdx.x & 63;
  const int sub = lane >> 3, fl = lane & 7;
  const int r = rb * RPB + (threadIdx.x >> 6);
  if (r >= n) return;
  float2 acc[2] = {{0.f,0.f},{0.f,0.f}};
  gather_row(rp, pk, b1 + slice * SW, r, sub, fl, acc);
  reduce_subs(acc);
  if (sub == 0) {
    const float c0 = coeffs[0];
    const size_t off = (size_t)r * FD + slice * SW;
    uint2 pr = nt_ld_u2((const uint2*)(b2 + off) + fl);
    const __half2* ph = (const __half2*)&pr;
    float2 p0 = __half22float2(ph[0]), p1 = __half22float2(ph[1]);
    float4 x = nt_ld_f4((const float4*)(X + off) + fl);
    float4 o;
    o.x = fmaf(c0, x.x, acc[0].x - p0.x);
    o.y = fmaf(c0, x.y, acc[0].y - p0.y);
    o.z = fmaf(c0, x.z, acc[1].x - p1.x);
    o.w = fmaf(c0, x.w, acc[1].y - p1.y);
    nt_st_f4((float4*)(out + off) + fl, o);
  }
}

// ---------------- launch ----------------

extern "C" void kernel_launch(void* const* d_in, const int* in_sizes, int n_in,
                              void* d_out, int out_size, void* d_ws, size_t ws_size,
                              hipStream_t stream) {
  const int* rows = (const int*)d_in[0];
  const int* cols = (const int*)d_in[1];
  const float* vals = (const float*)d_in[2];
  const float* X = (const float*)d_in[3];
  const float* coeffs = (const float*)d_in[4];
  float* out = (float*)d_out;

  const int nnz = in_sizes[0];
  const int n = in_sizes[3] / FD;
  const int M = in_sizes[4];

  auto align_up = [](size_t x) { return (x + 255) & ~(size_t)255; };
  char* w = (char*)d_ws;
  size_t off = 0;
  int* row_ptr = (int*)(w + off); off = align_up(off + (size_t)(n + 1) * 4);
  int* row_fill = (int*)(w + off); off = align_up(off + (size_t)n * 4);
  int* bsum = (int*)(w + off); off = align_up(off + 1024 * 4);
  int* bpre = (int*)(w + off); off = align_up(off + 1024 * 4);
  int2* pk = (int2*)(w + off); off = align_up(off + (size_t)nnz * 8);
  __half* Xh = (__half*)(w + off); off = align_up(off + (size_t)n * FD * 2);
  __half* buf0 = (__half*)(w + off); off = align_up(off + (size_t)n * FD * 2);
  __half* buf1 = (__half*)(w + off); off = align_up(off + (size_t)n * FD * 2);
  __half* bufs[2] = {buf0, buf1};
  (void)ws_size;

  const int B = 256;
  const int gN = (n + B - 1) / B;
  const int gE = (nnz + B - 1) / B;
  const int rbs = (n + RPB - 1) / RPB;
  const int gS = 8 * ((rbs + 1) / 2);   // 4 slices x rbs row-blocks, XCD-pinned
  const int n4 = n * FD / 4;
  const int gC = (n4 + B - 1) / B;

  // CSR build
  zero_i32<<<gN, B, 0, stream>>>(row_fill, n);
  hist_kernel<<<gE, B, 0, stream>>>(rows, row_fill, nnz);
  block_reduce<<<gN, B, 0, stream>>>(row_fill, bsum, n);
  scan_bsum<<<1, 1024, 0, stream>>>(bsum, bpre, gN);
  block_scan<<<gN, B, 0, stream>>>(row_fill, bpre, row_ptr, n);
  copy_i32<<<gN, B, 0, stream>>>(row_ptr, row_fill, n);
  scatter_kernel<<<gE, B, 0, stream>>>(rows, cols, vals, row_fill, pk, nnz);
  f32_to_f16<<<gC, B, 0, stream>>>(X, Xh, n4);

  // Clenshaw (b_{M-1} = c_{M-1} X eliminated algebraically; M >= 4):
  // k = M-2: b = 2 c_{M-1} (L Xh) + c_{M-2} X            [flags = 4]
  // k = M-3: b = 2 (L b_{M-2}) + (c_{M-3} - c_{M-1}) X   [flags = 2]
  // k = M-4..1: b = 2 (L b_{k+1}) - b_{k+2} + c_k X      [flags = 1]
  // out = c0 X + L b1 - b2
  clen_step<<<gS, B, 0, stream>>>(row_ptr, pk, Xh, Xh, bufs[(M - 2) & 1],
                                  coeffs, M - 2, 4, M, n, rbs);
  clen_step<<<gS, B, 0, stream>>>(row_ptr, pk, bufs[(M - 2) & 1], Xh, bufs[(M - 3) & 1],
                                  coeffs, M - 3, 2, M, n, rbs);
  for (int k = M - 4; k >= 1; --k) {
    clen_step<<<gS, B, 0, stream>>>(row_ptr, pk, bufs[(k + 1) & 1], Xh, bufs[k & 1],
                                    coeffs, k, 1, M, n, rbs);
  }
  clen_final<<<gS, B, 0, stream>>>(row_ptr, pk, bufs[1], bufs[0], X, out, coeffs, n, rbs);
}

// Round 2
// 1314.489 us; speedup vs baseline: 2.3471x; 2.3471x over previous
//
#include <hip/hip_runtime.h>
#include <hip/hip_fp16.h>

#define FD 128          // feature dim
#define RPB 4           // rows (waves) per block; block = 256 threads
// NOTE: algebraic elimination of b_{M-1} assumes M >= 4 (here M = 30).

// ---------------- CSR build ----------------

__global__ void zero_i32(int* __restrict__ p, int n) {
  int i = blockIdx.x * blockDim.x + threadIdx.x;
  if (i < n) p[i] = 0;
}

__global__ void hist_kernel(const int* __restrict__ rows, int* __restrict__ cnt, int nnz) {
  int i = blockIdx.x * blockDim.x + threadIdx.x;
  if (i < nnz) atomicAdd(&cnt[rows[i]], 1);
}

// coalesced 3-phase scan
__global__ void block_reduce(const int* __restrict__ cnt, int* __restrict__ bsum, int n) {
  __shared__ int sm[256];
  int i = blockIdx.x * 256 + threadIdx.x;
  sm[threadIdx.x] = (i < n) ? cnt[i] : 0;
  __syncthreads();
  for (int off = 128; off > 0; off >>= 1) {
    if (threadIdx.x < off) sm[threadIdx.x] += sm[threadIdx.x + off];
    __syncthreads();
  }
  if (threadIdx.x == 0) bsum[blockIdx.x] = sm[0];
}

__global__ void scan_bsum(const int* __restrict__ bsum, int* __restrict__ bpre, int nb) {
  __shared__ int sm[1024];
  const int tid = threadIdx.x;
  sm[tid] = (tid < nb) ? bsum[tid] : 0;
  __syncthreads();
  for (int off = 1; off < 1024; off <<= 1) {
    int t = (tid >= off) ? sm[tid - off] : 0;
    __syncthreads();
    sm[tid] += t;
    __syncthreads();
  }
  if (tid < nb) bpre[tid] = (tid == 0) ? 0 : sm[tid - 1];
}

__global__ void block_scan(const int* __restrict__ cnt, const int* __restrict__ bpre,
                           int* __restrict__ row_ptr, int n) {
  __shared__ int sm[256];
  const int tid = threadIdx.x;
  int i = blockIdx.x * 256 + tid;
  sm[tid] = (i < n) ? cnt[i] : 0;
  __syncthreads();
  for (int off = 1; off < 256; off <<= 1) {
    int t = (tid >= off) ? sm[tid - off] : 0;
    __syncthreads();
    sm[tid] += t;
    __syncthreads();
  }
  if (i < n) row_ptr[i + 1] = sm[tid] + bpre[blockIdx.x];
  if (i == 0) row_ptr[0] = 0;
}

__global__ void copy_i32(const int* __restrict__ src, int* __restrict__ dst, int n) {
  int i = blockIdx.x * blockDim.x + threadIdx.x;
  if (i < n) dst[i] = src[i];
}

// packed edge scatter: one 8B store per edge (at the write-allocate floor)
__global__ void scatter_kernel(const int* __restrict__ rows, const int* __restrict__ cols,
                               const float* __restrict__ vals, int* __restrict__ fill,
                               int2* __restrict__ pk, int nnz) {
  int i = blockIdx.x * blockDim.x + threadIdx.x;
  if (i < nnz) {
    int r = rows[i];
    int pos = atomicAdd(&fill[r], 1);
    pk[pos] = make_int2(cols[i], __float_as_int(vals[i]));
  }
}

// per-row bitonic sort of edges by column (wave = 1 row, deg <= 64).
// Sorting is a PERF-ONLY transform: all resident waves then sweep column
// space in lockstep, shrinking the instantaneous gather working set so it
// fits per-XCD L2. deg > 64 rows are left unsorted (correct, just slower).
__global__ __launch_bounds__(256) void sort_row_edges(const int* __restrict__ rp,
                                                      int2* __restrict__ pk, int n) {
  const int r = blockIdx.x * RPB + (threadIdx.x >> 6);
  if (r >= n) return;
  const int lane = threadIdx.x & 63;
  const int s = rp[r], e = rp[r + 1];
  const int d = e - s;
  if (d <= 1 || d > 64) return;
  int2 cv = (lane < d) ? pk[s + lane] : make_int2(0x7fffffff, 0);
#pragma unroll
  for (int k = 2; k <= 64; k <<= 1) {
#pragma unroll
    for (int j = k >> 1; j >= 1; j >>= 1) {
      int px = __shfl_xor(cv.x, j, 64);
      int py = __shfl_xor(cv.y, j, 64);
      const bool asc = ((lane & k) == 0);
      const bool lower = ((lane & j) == 0);
      const bool keepMin = (asc == lower);
      const bool take = keepMin ? (px < cv.x) : (px > cv.x);
      if (take) { cv.x = px; cv.y = py; }
    }
  }
  if (lane < d) pk[s + lane] = cv;
}

__global__ void f32_to_f16(const float* __restrict__ src, __half* __restrict__ dst, int n4) {
  int i = blockIdx.x * blockDim.x + threadIdx.x;
  if (i < n4) {
    float4 v = ((const float4*)src)[i];
    __half2* d = (__half2*)dst + 2 * (size_t)i;
    d[0] = __floats2half2_rn(v.x, v.y);
    d[1] = __floats2half2_rn(v.z, v.w);
  }
}

// ---------------- nontemporal helpers (protect the L2 gather window) ----------------

typedef int v2i __attribute__((ext_vector_type(2)));
typedef unsigned int v4u __attribute__((ext_vector_type(4)));
typedef float v4f __attribute__((ext_vector_type(4)));

__device__ __forceinline__ int2 nt_ld_i2(const int2* p) {
  v2i v = __builtin_nontemporal_load((const v2i*)p);
  return make_int2(v.x, v.y);
}
__device__ __forceinline__ uint4 nt_ld_u4(const uint4* p) {
  v4u v = __builtin_nontemporal_load((const v4u*)p);
  return make_uint4(v.x, v.y, v.z, v.w);
}
__device__ __forceinline__ float4 nt_ld_f4(const float4* p) {
  v4f v = __builtin_nontemporal_load((const v4f*)p);
  return make_float4(v.x, v.y, v.z, v.w);
}
__device__ __forceinline__ void nt_st_f4(float4* p, float4 x) {
  v4f v = {x.x, x.y, x.z, x.w};
  __builtin_nontemporal_store(v, (v4f*)p);
}

// ---------------- wide gather (R7-proven shape) ----------------
// Wave = 1 row. sub = lane>>4 picks 1 of 4 edges; fl = lane&15 picks an 8-feature
// quad (uint4 = 16B). One load instruction covers 4 edges x 256B = 1024B.
// Gather loads are CACHED (the whole point); pk edge loads are nontemporal.

__device__ __forceinline__ void fma_edge(const __half* __restrict__ T, int c, float v,
                                         int fl, float2 acc[4]) {
  uint4 raw = ((const uint4*)(T + (size_t)c * FD))[fl];
  const __half2* h = (const __half2*)&raw;
  float2 x0 = __half22float2(h[0]);
  float2 x1 = __half22float2(h[1]);
  float2 x2 = __half22float2(h[2]);
  float2 x3 = __half22float2(h[3]);
  acc[0].x = fmaf(v, x0.x, acc[0].x); acc[0].y = fmaf(v, x0.y, acc[0].y);
  acc[1].x = fmaf(v, x1.x, acc[1].x); acc[1].y = fmaf(v, x1.y, acc[1].y);
  acc[2].x = fmaf(v, x2.x, acc[2].x); acc[2].y = fmaf(v, x2.y, acc[2].y);
  acc[3].x = fmaf(v, x3.x, acc[3].x); acc[3].y = fmaf(v, x3.y, acc[3].y);
}

__device__ __forceinline__ void gather_row(const int* __restrict__ rp,
                                           const int2* __restrict__ pk,
                                           const __half* __restrict__ T,
                                           int r, int sub, int fl, float2 acc[4]) {
  int e = rp[r];
  const int end = rp[r + 1];
  for (; e + 8 <= end; e += 8) {
    int2 cv0 = nt_ld_i2(pk + e + sub);
    int2 cv1 = nt_ld_i2(pk + e + 4 + sub);
    fma_edge(T, cv0.x, __int_as_float(cv0.y), fl, acc);
    fma_edge(T, cv1.x, __int_as_float(cv1.y), fl, acc);
  }
  if (e + 4 <= end) {
    int2 cv = nt_ld_i2(pk + e + sub);
    fma_edge(T, cv.x, __int_as_float(cv.y), fl, acc);
    e += 4;
  }
  if (e < end) {
    int idx = e + sub;
    int2 cv = nt_ld_i2(pk + min(idx, end - 1));
    float v = (idx < end) ? __int_as_float(cv.y) : 0.f;
    fma_edge(T, cv.x, v, fl, acc);
  }
}

__device__ __forceinline__ void reduce_subs(float2 acc[4]) {
#pragma unroll
  for (int m = 16; m < 64; m <<= 1) {
#pragma unroll
    for (int q = 0; q < 4; ++q) {
      acc[q].x += __shfl_xor(acc[q].x, m, 64);
      acc[q].y += __shfl_xor(acc[q].y, m, 64);
    }
  }
}

// ---------------- Clenshaw steps ----------------
// b_k = g2*(L @ src) - p + ck_eff * X   (fp16 state, fp32 math)
// flags: bit0 = read p from pd; bit1 = ck_eff = c_k - c_{M-1} (folds b_{M-1});
//        bit2 = g2 = 2*c_{M-1} (src is Xh standing in for b_{M-1} = c_{M-1} X).
// pd holds b_{k+2} and receives b_k (same element, same lane -> safe in-place).

__global__ __launch_bounds__(256) void clen_step(
    const int* __restrict__ rp, const int2* __restrict__ pk,
    const __half* __restrict__ src, const __half* __restrict__ Xh, __half* pd,
    const float* __restrict__ coeffs, int k, int flags, int M, int n) {
  const int lane = threadIdx.x & 63;
  const int sub = lane >> 4, fl = lane & 15;
  const int r = blockIdx.x * RPB + (threadIdx.x >> 6);
  if (r >= n) return;
  float2 acc[4] = {{0.f,0.f},{0.f,0.f},{0.f,0.f},{0.f,0.f}};
  gather_row(rp, pk, src, r, sub, fl, acc);
  reduce_subs(acc);
  if (sub == 0) {
    float ck = coeffs[k];
    if (flags & 2) ck -= coeffs[M - 1];
    const float g2 = (flags & 4) ? 2.f * coeffs[M - 1] : 2.f;
    uint4 xr = nt_ld_u4((const uint4*)(Xh + (size_t)r * FD) + fl);
    const __half2* xh = (const __half2*)&xr;
    float2 p[4] = {{0.f,0.f},{0.f,0.f},{0.f,0.f},{0.f,0.f}};
    if (flags & 1) {
      uint4 pr = nt_ld_u4((const uint4*)(pd + (size_t)r * FD) + fl);
      const __half2* ph = (const __half2*)&pr;
#pragma unroll
      for (int q = 0; q < 4; ++q) p[q] = __half22float2(ph[q]);
    }
    uint4 orr;
    __half2* oh = (__half2*)&orr;
#pragma unroll
    for (int q = 0; q < 4; ++q) {
      float2 x = __half22float2(xh[q]);
      float tx = fmaf(g2, acc[q].x, fmaf(ck, x.x, -p[q].x));
      float ty = fmaf(g2, acc[q].y, fmaf(ck, x.y, -p[q].y));
      oh[q] = __floats2half2_rn(tx, ty);
    }
    ((uint4*)(pd + (size_t)r * FD))[fl] = orr;   // cached: gathered next step
  }
}

// out = c0*X + L @ b1 - b2   (fp32 X and output)
__global__ __launch_bounds__(256) void clen_final(
    const int* __restrict__ rp, const int2* __restrict__ pk,
    const __half* __restrict__ b1, const __half* __restrict__ b2,
    const float* __restrict__ X, float* __restrict__ out,
    const float* __restrict__ coeffs, int n) {
  const int lane = threadIdx.x & 63;
  const int sub = lane >> 4, fl = lane & 15;
  const int r = blockIdx.x * RPB + (threadIdx.x >> 6);
  if (r >= n) return;
  float2 acc[4] = {{0.f,0.f},{0.f,0.f},{0.f,0.f},{0.f,0.f}};
  gather_row(rp, pk, b1, r, sub, fl, acc);
  reduce_subs(acc);
  if (sub == 0) {
    const float c0 = coeffs[0];
    uint4 pr = nt_ld_u4((const uint4*)(b2 + (size_t)r * FD) + fl);
    const __half2* ph = (const __half2*)&pr;
    float4 x0 = nt_ld_f4((const float4*)(X + (size_t)r * FD) + fl * 2);
    float4 x1 = nt_ld_f4((const float4*)(X + (size_t)r * FD) + fl * 2 + 1);
    float2 p0 = __half22float2(ph[0]), p1 = __half22float2(ph[1]);
    float2 p2 = __half22float2(ph[2]), p3 = __half22float2(ph[3]);
    float4 o0, o1;
    o0.x = fmaf(c0, x0.x, acc[0].x - p0.x);
    o0.y = fmaf(c0, x0.y, acc[0].y - p0.y);
    o0.z = fmaf(c0, x0.z, acc[1].x - p1.x);
    o0.w = fmaf(c0, x0.w, acc[1].y - p1.y);
    o1.x = fmaf(c0, x1.x, acc[2].x - p2.x);
    o1.y = fmaf(c0, x1.y, acc[2].y - p2.y);
    o1.z = fmaf(c0, x1.z, acc[3].x - p3.x);
    o1.w = fmaf(c0, x1.w, acc[3].y - p3.y);
    nt_st_f4((float4*)(out + (size_t)r * FD) + fl * 2, o0);
    nt_st_f4((float4*)(out + (size_t)r * FD) + fl * 2 + 1, o1);
  }
}

// ---------------- launch ----------------

extern "C" void kernel_launch(void* const* d_in, const int* in_sizes, int n_in,
                              void* d_out, int out_size, void* d_ws, size_t ws_size,
                              hipStream_t stream) {
  const int* rows = (const int*)d_in[0];
  const int* cols = (const int*)d_in[1];
  const float* vals = (const float*)d_in[2];
  const float* X = (const float*)d_in[3];
  const float* coeffs = (const float*)d_in[4];
  float* out = (float*)d_out;

  const int nnz = in_sizes[0];
  const int n = in_sizes[3] / FD;
  const int M = in_sizes[4];

  auto align_up = [](size_t x) { return (x + 255) & ~(size_t)255; };
  char* w = (char*)d_ws;
  size_t off = 0;
  int* row_ptr = (int*)(w + off); off = align_up(off + (size_t)(n + 1) * 4);
  int* row_fill = (int*)(w + off); off = align_up(off + (size_t)n * 4);
  int* bsum = (int*)(w + off); off = align_up(off + 1024 * 4);
  int* bpre = (int*)(w + off); off = align_up(off + 1024 * 4);
  int2* pk = (int2*)(w + off); off = align_up(off + (size_t)nnz * 8);
  __half* Xh = (__half*)(w + off); off = align_up(off + (size_t)n * FD * 2);
  __half* buf0 = (__half*)(w + off); off = align_up(off + (size_t)n * FD * 2);
  __half* buf1 = (__half*)(w + off); off = align_up(off + (size_t)n * FD * 2);
  __half* bufs[2] = {buf0, buf1};
  (void)ws_size;

  const int B = 256;
  const int gN = (n + B - 1) / B;
  const int gE = (nnz + B - 1) / B;
  const int gS = (n + RPB - 1) / RPB;
  const int n4 = n * FD / 4;
  const int gC = (n4 + B - 1) / B;

  // CSR build
  zero_i32<<<gN, B, 0, stream>>>(row_fill, n);
  hist_kernel<<<gE, B, 0, stream>>>(rows, row_fill, nnz);
  block_reduce<<<gN, B, 0, stream>>>(row_fill, bsum, n);
  scan_bsum<<<1, 1024, 0, stream>>>(bsum, bpre, gN);
  block_scan<<<gN, B, 0, stream>>>(row_fill, bpre, row_ptr, n);
  copy_i32<<<gN, B, 0, stream>>>(row_ptr, row_fill, n);
  scatter_kernel<<<gE, B, 0, stream>>>(rows, cols, vals, row_fill, pk, nnz);
  sort_row_edges<<<gS, B, 0, stream>>>(row_ptr, pk, n);
  f32_to_f16<<<gC, B, 0, stream>>>(X, Xh, n4);

  // Clenshaw (b_{M-1} = c_{M-1} X eliminated algebraically; M >= 4):
  // k = M-2: b = 2 c_{M-1} (L Xh) + c_{M-2} X            [flags = 4]
  // k = M-3: b = 2 (L b_{M-2}) + (c_{M-3} - c_{M-1}) X   [flags = 2]
  // k = M-4..1: b = 2 (L b_{k+1}) - b_{k+2} + c_k X      [flags = 1]
  // out = c0 X + L b1 - b2
  clen_step<<<gS, B, 0, stream>>>(row_ptr, pk, Xh, Xh, bufs[(M - 2) & 1],
                                  coeffs, M - 2, 4, M, n);
  clen_step<<<gS, B, 0, stream>>>(row_ptr, pk, bufs[(M - 2) & 1], Xh, bufs[(M - 3) & 1],
                                  coeffs, M - 3, 2, M, n);
  for (int k = M - 4; k >= 1; --k) {
    clen_step<<<gS, B, 0, stream>>>(row_ptr, pk, bufs[(k + 1) & 1], Xh, bufs[k & 1],
                                    coeffs, k, 1, M, n);
  }
  clen_final<<<gS, B, 0, stream>>>(row_ptr, pk, bufs[1], bufs[0], X, out, coeffs, n);
}